// Round 8
// baseline (350.192 us; speedup 1.0000x reference)
//
#include <hip/hip_runtime.h>
#include <stdint.h>

// MarkovChain FFBS: B=64, T=1024, K=512, I=4
// R19 = R16 core + phase-overlapped pipeline (R17's overlap goal achieved
// via DISPATCH BOUNDARIES, not spin-gates -- R17's polling was a
// same-address atomic storm, 2.2ms; R18's chain-spreading doubled FETCH
// and is reverted: same-run chains back on one block).
//   4 phase launches; backward units partitioned by need-level
//   (need = min(len,lmax)-1; partition B:{0} C:[1,av1-1] D:[av1,av2-1]
//   E:[av2,lmax-1]):
//   L1: GEMM P^2 (272 blk) || sort (129) || need-0 units + fill_out (4096)
//   L2: GEMM P^3,P^4 (544) || need-1 units (P^2 ready by stream order)
//   L3: GEMM P^5,P^6 (544) || need-2,3 units
//   L4: need>=4 units, LPT from runsSorted, R16 block=run mapping
//   GEMM/sort hide under bwd VALU work; per-phase uniform lengths kill
//   the drain tail; final phase's long chains run at full issue rate.
// Per-k values bit-identical to R11..R18 -> absmax 0.

#define JAX_PARTITIONABLE 1

#define B_ 64
#define T_ 1024
#define K_ 512
#define I_ 4
#define NCHAIN (B_ * I_)
#define POWSLOT (513 * 512)   // rows 0..511 = P^L, row 512 = init_p @ P^L
#define LMAX_WANT 6
#define MAXRUNS 32769
#define GEMM_TILES 272        // 17*16 tiles of 32x32 covering 513x512
#define SORT_BLOCKS 129       // ceil(MAXRUNS / 256)
#define BWD_PHASE_BLOCKS 4096
#define FINAL_BLOCKS 2048

typedef double f64x4 __attribute__((ext_vector_type(4)));

// ---------------- Threefry-2x32-20 (exact jax semantics) ----------------
__host__ __device__ inline void tf2x32(uint32_t k0, uint32_t k1, uint32_t c0, uint32_t c1,
                                       uint32_t& o0, uint32_t& o1) {
  uint32_t ks2 = k0 ^ k1 ^ 0x1BD11BDAu;
  uint32_t x0 = c0 + k0;
  uint32_t x1 = c1 + k1;
#define TFR(r) { x0 += x1; x1 = (x1 << (r)) | (x1 >> (32 - (r))); x1 ^= x0; }
  TFR(13) TFR(15) TFR(26) TFR(6)
  x0 += k1; x1 += ks2 + 1u;
  TFR(17) TFR(29) TFR(16) TFR(24)
  x0 += ks2; x1 += k0 + 2u;
  TFR(13) TFR(15) TFR(26) TFR(6)
  x0 += k0; x1 += k1 + 3u;
  TFR(17) TFR(29) TFR(16) TFR(24)
  x0 += k1; x1 += ks2 + 4u;
  TFR(13) TFR(15) TFR(26) TFR(6)
  x0 += ks2; x1 += k0 + 5u;
#undef TFR
  o0 = x0; o1 = x1;
}

__device__ inline uint32_t rng_bits(uint32_t kj0, uint32_t kj1, uint32_t e) {
#if JAX_PARTITIONABLE
  uint32_t a, b;
  tf2x32(kj0, kj1, 0u, e, a, b);
  return a ^ b;
#else
  const uint32_t HALF = (uint32_t)(NCHAIN * K_ / 2);
  uint32_t a, b;
  if (e < HALF) { tf2x32(kj0, kj1, e, e + HALF, a, b); return a; }
  else          { tf2x32(kj0, kj1, e - HALF, e, a, b); return b; }
#endif
}

// gumbel scale factor: G = -1/log(u) > 0, so that w*G is a monotone image of
// log(w) + (-log(-log u)). Branch-free log, <=2ulp RELATIVE everywhere.
__device__ inline float gumbel_scale(uint32_t bits) {
  float f = __uint_as_float((bits >> 9) | 0x3F800000u) - 1.0f;
  float u = f + 1.17549435e-38f;            // u in [2^-126, 1)
  int iu = __float_as_int(u);
  float ef = (float)((iu >> 23) - 127);
  float m = __int_as_float((iu & 0x007fffff) | 0x3f800000);   // [1,2)
  int big = m > 1.41421356f;                // reduce to [~0.707, ~1.414)
  m = big ? m * 0.5f : m;
  ef = big ? ef + 1.0f : ef;
  float fm = m - 1.0f;                      // exact (Sterbenz)
  float r = fm * __builtin_amdgcn_rcpf(m + 1.0f);   // atanh arg, |r|<=0.172
  float r2 = r * r;
  float p = fmaf(r2, fmaf(r2, fmaf(r2, fmaf(r2, 0.11111111f, 0.14285715f),
                                   0.2f), 0.33333334f), 1.0f);
  float logu = fmaf(ef, 0.69314718f, (r + r) * p);  // < 0 strictly
  return -__builtin_amdgcn_rcpf(logu);
}

__device__ inline void step_key(uint32_t ks0, uint32_t ks1, int j, uint32_t& kj0, uint32_t& kj1) {
#if JAX_PARTITIONABLE
  tf2x32(ks0, ks1, 0u, (uint32_t)j, kj0, kj1);
#else
  const int N = T_ - 1;
  uint32_t o0, o1;
  int v = 2 * j;
  if (v < N) { tf2x32(ks0, ks1, (uint32_t)v, (uint32_t)(v + N), o0, o1); kj0 = o0; }
  else       { tf2x32(ks0, ks1, (uint32_t)(v - N), (uint32_t)v, o0, o1); kj0 = o1; }
  v = 2 * j + 1;
  if (v < N) { tf2x32(ks0, ks1, (uint32_t)v, (uint32_t)(v + N), o0, o1); kj1 = o0; }
  else       { tf2x32(ks0, ks1, (uint32_t)(v - N), (uint32_t)v, o0, o1); kj1 = o1; }
#endif
}

// ---------------- Merged setup: offsets scan + transpose + V1 + keys ----------------
// Header pre-zeroed via hipMemsetAsync.
__global__ __launch_bounds__(1024) void setup_all(
    const int* __restrict__ data, const float* __restrict__ masks,
    const float* __restrict__ P, const float* __restrict__ initp,
    float* __restrict__ POW0, float* __restrict__ PTp,
    float* __restrict__ INITROW, float* __restrict__ V1,
    int* __restrict__ off, int lmax, int initoff,
    int* __restrict__ runs, int* __restrict__ runCount, int* __restrict__ maxLdev,
    int* __restrict__ hist,
    uint32_t* __restrict__ KEY0, uint32_t* __restrict__ KEY1,
    uint32_t ks0, uint32_t ks1) {
  int blk = blockIdx.x;
  int tid = threadIdx.x;
  if (blk < 64) {
    __shared__ int prevObs[1024];
    __shared__ int nextObs[1024];
    __shared__ int lhist[64];
    __shared__ int lmaxL;
    int b = blk;
    int t = tid;
    bool obs = masks[b * T_ + t] > 0.0f;
    prevObs[t] = obs ? t : -1;
    nextObs[t] = obs ? t : T_;
    if (t < 64) lhist[t] = 0;
    if (t == 0) lmaxL = 1;
    __syncthreads();
    for (int o = 1; o < 1024; o <<= 1) {
      int pv = (t >= o) ? prevObs[t - o] : -1;
      int nv = (t + o < 1024) ? nextObs[t + o] : T_;
      __syncthreads();
      if (pv > prevObs[t]) prevObs[t] = pv;
      if (nv < nextObs[t]) nextObs[t] = nv;
      __syncthreads();
    }
    int t0 = (t > 0) ? prevObs[t - 1] : -1;
    int idx = b * T_ + t;
    if (obs) off[idx] = -1;
    else if (t0 >= 0) {
      int L = t - t0; if (L > lmax) L = lmax;
      off[idx] = (L - 1) * POWSLOT + data[b * T_ + t0] * 512;
    } else if (t == 0) off[idx] = initoff;
    else {
      int L = t; if (L > lmax) L = lmax;
      off[idx] = (L - 1) * POWSLOT + 512 * 512;   // init-chain V row
    }
    if (!obs && t <= T_ - 2 && (t == 0 || masks[b * T_ + t - 1] > 0.0f)) {
      int te = nextObs[t] - 1; if (te > T_ - 2) te = T_ - 2;
      int r = atomicAdd(runCount, 1);   // uniform addr, +1 -> wave-coalesced
      if (r < MAXRUNS) {
        runs[r] = (b << 20) | (t << 10) | te;
        int steps = te - t + 1;
        int bkt = steps < 63 ? steps : 63;
        atomicAdd(&lhist[bkt], 1);                 // LDS atomic
        int maxL = (t == 0) ? te : (te - t + 1);
        if (maxL > 1) atomicMax(&lmaxL, maxL);     // LDS atomic
      }
    }
    __syncthreads();
    if (t < 64) {
      int c = lhist[t];
      if (c) atomicAdd(&hist[t], c);               // 64 distinct addresses
    }
    if (t == 0) {
      int v = lmaxL;
      if (v > 1) atomicMax(maxLdev, v);            // one per block
    }
  } else if (blk < 128) {
    // 64x64 tile transpose, both sides coalesced; POW0 copy reuses the load.
    __shared__ float Tls[64][65];
    int tt = blk - 64, tr = tt >> 3, tc = tt & 7;
    int r = tid >> 4, c4 = (tid & 15) << 2;
    int src = ((tr << 6) + r) * 512 + (tc << 6) + c4;
    float4 v = *(const float4*)(P + src);
    *(float4*)(POW0 + src) = v;
    Tls[c4 + 0][r] = v.x;
    Tls[c4 + 1][r] = v.y;
    Tls[c4 + 2][r] = v.z;
    Tls[c4 + 3][r] = v.w;
    __syncthreads();
    const float q = 0.001953125f;   // + 1/K, bit-identical to inline add
    float4 w;
    w.x = Tls[r][c4 + 0] + q;
    w.y = Tls[r][c4 + 1] + q;
    w.z = Tls[r][c4 + 2] + q;
    w.w = Tls[r][c4 + 3] + q;
    *(float4*)(PTp + ((tc << 6) + r) * 512 + (tr << 6) + c4) = w;
  } else if (blk == 128) {
    // V1[c] = sum_j initp[j] * P[j][c], f64, split across 2 thread halves
    __shared__ double vred[512];
    int c = tid & 511, h = tid >> 9;
    const float* Ph = P + h * 256 * 512;
    const float* ih = initp + h * 256;
    double acc = 0.0;
    for (int j = 0; j < 256; ++j) acc += (double)ih[j] * (double)Ph[j * 512 + c];
    if (h == 0) vred[c] = acc;
    __syncthreads();
    if (h == 1) V1[c] = (float)(vred[c] + acc);
    if (tid < 512) INITROW[tid] = initp[tid];
  } else {
    if (tid < T_ - 1) {
      uint32_t a, b;
      step_key(ks0, ks1, tid, a, b);
      KEY0[tid] = a; KEY1[tid] = b;
    }
  }
}

// ---------------- GEMM tile (f64 MFMA, self-calibrating D layout) ----------------
__device__ __forceinline__ void gemm_tile(float* POW, int m, int y, int x,
                                          double (*As)[33], double (*Bs)[33],
                                          int tid, int gate) {
  if (y + 1 + m > gate) return;       // block-uniform
  const float* A  = POW + (size_t)y * POWSLOT;
  const float* Bm = POW + (size_t)(m - 1) * POWSLOT;
  float* C        = POW + (size_t)(y + m) * POWSLOT;
  int lane = tid & 63;
  int wv = tid >> 6;
  int wr = wv >> 1, wc = wv & 1;
  int q = lane >> 4, r16 = lane & 15;
  int r0 = (x >> 4) * 32;
  int c0 = (x & 15) * 32;
  f64x4 z = {0.0, 0.0, 0.0, 0.0};
  f64x4 d1 = __builtin_amdgcn_mfma_f64_16x16x4f64((double)r16, 1.0, z, 0, 0, 0);   // D=4i
  f64x4 d2 = __builtin_amdgcn_mfma_f64_16x16x4f64(1.0, (double)r16, z, 0, 0, 0);   // D=4j
  int ir[4], ic[4];
#pragma unroll
  for (int v = 0; v < 4; ++v) {
    ir[v] = (((int)d1[v]) >> 2) & 15;
    ic[v] = (((int)d2[v]) >> 2) & 15;
  }
  int sr = tid >> 3;
  int sk4 = (tid & 7) * 4;
  int ar = r0 + sr; if (ar > 512) ar = 512;
  f64x4 acc = {0.0, 0.0, 0.0, 0.0};
  float4 av = *(const float4*)(A + (size_t)ar * 512 + sk4);
  float4 bv = *(const float4*)(Bm + (size_t)sr * 512 + c0 + sk4);
  for (int kc = 0; kc < 512; kc += 32) {
    __syncthreads();                 // previous chunk's LDS reads done
    As[sk4 + 0][sr] = (double)av.x;
    As[sk4 + 1][sr] = (double)av.y;
    As[sk4 + 2][sr] = (double)av.z;
    As[sk4 + 3][sr] = (double)av.w;
    Bs[sr][sk4 + 0] = (double)bv.x;
    Bs[sr][sk4 + 1] = (double)bv.y;
    Bs[sr][sk4 + 2] = (double)bv.z;
    Bs[sr][sk4 + 3] = (double)bv.w;
    int kn = (kc + 32 < 512) ? kc + 32 : 480;  // clamped (last prefetch unused)
    av = *(const float4*)(A + (size_t)ar * 512 + kn + sk4);
    bv = *(const float4*)(Bm + (size_t)(kn + sr) * 512 + c0 + sk4);
    __syncthreads();
#pragma unroll
    for (int ks = 0; ks < 8; ++ks) {
      double a = As[ks * 4 + q][wr * 16 + r16];
      double b = Bs[ks * 4 + q][wc * 16 + r16];
      acc = __builtin_amdgcn_mfma_f64_16x16x4f64(a, b, acc, 0, 0, 0);
    }
  }
#pragma unroll
  for (int v = 0; v < 4; ++v) {
    int gr = r0 + wr * 16 + ir[v];
    int gc = c0 + wc * 16 + ic[v];
    if (gr < 513) C[(size_t)gr * 512 + gc] = (float)acc[v];
  }
}

// ---------------- Backward unit (bit-identical math to R11..R18) ----------------
__device__ __forceinline__ void bwd_unit(
    int run, int ci, int lane,
    const int* __restrict__ data, const float* wsF,
    const int* __restrict__ off, const float* PTp,
    const uint32_t* __restrict__ KEY0, const uint32_t* __restrict__ KEY1,
    int* __restrict__ out) {
  int b = run >> 20, ta = (run >> 10) & 1023, tb = run & 1023;
  const float* wsL = wsF + (lane << 3);
  const float* ptL = PTp + (lane << 3);
  int s = data[b * T_ + tb + 1];    // mask=1 or t=T-1: deterministic anchor
  uint32_t ebase = ((uint32_t)b << 11) | ((uint32_t)ci << 9) | ((uint32_t)(lane << 3));
  const int* offb = off + b * T_;
  int* outp = out + (((b << 2) | ci) * T_);
  for (int t = tb; t >= ta; --t) {
    int j = (T_ - 2) - t;
    uint32_t kj0 = KEY0[j], kj1 = KEY1[j];
    int o = offb[t];
    float4 m0 = *(const float4*)(wsL + o);
    float4 m1 = *(const float4*)(wsL + o + 4);
    const float* prow = ptL + ((size_t)s << 9);
    float4 p0 = *(const float4*)(prow);
    float4 p1 = *(const float4*)(prow + 4);
    float x0 = fmaf(m0.x, p0.x, 1e-20f) * gumbel_scale(rng_bits(kj0, kj1, ebase + 0u));
    float x1 = fmaf(m0.y, p0.y, 1e-20f) * gumbel_scale(rng_bits(kj0, kj1, ebase + 1u));
    float x2 = fmaf(m0.z, p0.z, 1e-20f) * gumbel_scale(rng_bits(kj0, kj1, ebase + 2u));
    float x3 = fmaf(m0.w, p0.w, 1e-20f) * gumbel_scale(rng_bits(kj0, kj1, ebase + 3u));
    float x4 = fmaf(m1.x, p1.x, 1e-20f) * gumbel_scale(rng_bits(kj0, kj1, ebase + 4u));
    float x5 = fmaf(m1.y, p1.y, 1e-20f) * gumbel_scale(rng_bits(kj0, kj1, ebase + 5u));
    float x6 = fmaf(m1.z, p1.z, 1e-20f) * gumbel_scale(rng_bits(kj0, kj1, ebase + 6u));
    float x7 = fmaf(m1.w, p1.w, 1e-20f) * gumbel_scale(rng_bits(kj0, kj1, ebase + 7u));
    float bv = x0; int bj = 0;
    if (x1 > bv) { bv = x1; bj = 1; }
    if (x2 > bv) { bv = x2; bj = 2; }
    if (x3 > bv) { bv = x3; bj = 3; }
    if (x4 > bv) { bv = x4; bj = 4; }
    if (x5 > bv) { bv = x5; bj = 5; }
    if (x6 > bv) { bv = x6; bj = 6; }
    if (x7 > bv) { bv = x7; bj = 7; }
    float wm = bv;
#pragma unroll
    for (int d = 1; d < 64; d <<= 1) wm = fmaxf(wm, __shfl_xor(wm, d));
    unsigned long long bal = __ballot(bv == wm);
    int wl = __ffsll(bal) - 1;       // lowest lane with the max = smallest k
    int jw = __shfl(bj, wl);
    s = (wl << 3) + jw;              // uniform across wave
    if (lane == 0) outp[t] = s;
  }
}

// ---------------- Phase kernel: GEMM tiles + (sort) + need-gated backward ----------------
// All dependencies between phases are carried by DISPATCH ORDER (stream),
// never by in-kernel gating. Roles by blockIdx:
//   [0, gemmBlocks)                 : gemm_tile for this stage's power level(s)
//   [gemmBlocks, bwdBase)           : sort scatter (stage 1 only)
//   [bwdBase, gridDim)              : backward units with need in [needLo, needHi]
__global__ __launch_bounds__(256, 6) void phase_kernel(
    int stage, int gemmBlocks, int m, int bwdBase,
    int needLo, int needHi, int useSorted,
    const int* __restrict__ data, const float* __restrict__ masks,
    float* wsF, const int* __restrict__ off,
    const uint32_t* __restrict__ KEY0, const uint32_t* __restrict__ KEY1,
    const int* __restrict__ runsU, const int* __restrict__ runCount,
    const int* __restrict__ maxLdev, const int* __restrict__ hist,
    int* __restrict__ cursor, int* __restrict__ runsSorted,
    int* __restrict__ out, int lmax) {
  __shared__ double As[32][33];
  __shared__ double Bs[32][33];
  int blk = blockIdx.x;
  int tid = threadIdx.x;
  float* POW = wsF;
  const float* PTp = wsF + (size_t)lmax * POWSLOT;

  if (blk < gemmBlocks) {
    int gate = *maxLdev; if (gate > lmax) gate = lmax;
    gemm_tile(POW, m, blk / GEMM_TILES, blk % GEMM_TILES, As, Bs, tid, gate);
    return;
  }
  if (blk < bwdBase) {
    // stage-1 sort scatter: LDS-staged ranks, ONE global atomicAdd per
    // (block,bucket) -- no same-address storms (R14 lesson).
    int* ish = (int*)As;             // lhist2[64], gbase[64], sbase[64]
    int i = (blk - gemmBlocks) * 256 + tid;
    int total = *runCount; if (total > MAXRUNS) total = MAXRUNS;
    bool valid = i < total;
    if (tid < 64) ish[tid] = 0;
    __syncthreads();
    int r = 0, bkt = 0, lr = 0;
    if (valid) {
      r = runsU[i];
      int ta = (r >> 10) & 1023, tb = r & 1023;
      int steps = tb - ta + 1;
      bkt = steps < 63 ? steps : 63;
      lr = atomicAdd(&ish[bkt], 1);
    }
    __syncthreads();
    if (tid < 64) {
      int c = ish[tid];
      ish[64 + tid] = c ? atomicAdd(&cursor[tid], c) : 0;
      int s = 0;
      for (int l = tid + 1; l < 64; ++l) s += hist[l];
      ish[128 + tid] = s;
    }
    __syncthreads();
    if (valid) runsSorted[ish[128 + bkt] + ish[64 + bkt] + lr] = r;
    return;
  }

  // ---- backward role ----
  int bi = blk - bwdBase;
  if (stage == 1) {
    // folded fill_out: deterministic outputs (observed t, and t = T-1)
    int id = bi * 256 + tid;
    if (id < NCHAIN * T_) {
      int t = id & (T_ - 1);
      int b = id >> 12;
      if (t == T_ - 1 || masks[b * T_ + t] > 0.0f) out[id] = data[b * T_ + t];
    }
  }
  int lane = tid & 63;
  int wv = tid >> 6;
  int nb = gridDim.x - bwdBase;
  int NWp = nb * 4;
  int wid = bi * 4 + wv;               // block = 4 chains of one run (L2 share)
  int total = *runCount;
  if (total > MAXRUNS) total = MAXRUNS;
  int total4 = total << 2;
  const int* R = useSorted ? runsSorted : runsU;
  for (int u = wid; u < total4; u += NWp) {
    int run = R[u >> 2];
    int ta = (run >> 10) & 1023, tb = run & 1023;
    int s = tb - ta + 1;
    int nl = s > lmax ? lmax : s;
    int need = nl - 1;
    if (need < needLo || need > needHi) continue;
    bwd_unit(run, u & 3, lane, data, wsF, off, PTp, KEY0, KEY1, out);
  }
}

// ---------------- Launcher ----------------
extern "C" void kernel_launch(void* const* d_in, const int* in_sizes, int n_in,
                              void* d_out, int out_size, void* d_ws, size_t ws_size,
                              hipStream_t stream) {
  const int* data = (const int*)d_in[0];
  const float* masks = (const float*)d_in[1];
  const float* initp = (const float*)d_in[2];
  const float* P = (const float*)d_in[3];
  int* out = (int*)d_out;

  int lmax = LMAX_WANT;
  {
    long long fixed = 512LL * 512 + 512 + (long long)B_ * T_ + 2 * (T_ - 1)
                      + 2LL * MAXRUNS + 256;
    long long avail = (long long)(ws_size / 4) - fixed;
    long long fit = avail / POWSLOT;
    if (fit < lmax) lmax = (fit < 1) ? 1 : (int)fit;
  }
  float* wsF = (float*)d_ws;
  float* POW = wsF;
  float* PTp = wsF + (size_t)lmax * POWSLOT;
  float* INITROW = PTp + 512 * 512;
  int* off = (int*)(INITROW + 512);
  uint32_t* KEY0 = (uint32_t*)(off + B_ * T_);
  uint32_t* KEY1 = KEY0 + (T_ - 1);
  int* runs = (int*)(KEY1 + (T_ - 1));
  int* runCount = runs + MAXRUNS;     // header: [0] runCount, [1] maxLdev,
  int* maxLdev = runCount + 1;        // [2..65] hist, [66..129] cursor
  int* hist = runCount + 2;
  int* cursor = runCount + 66;
  int* runsSorted = runCount + 130;
  int initoff = lmax * POWSLOT + 512 * 512;   // INITROW position in floats

  // stage plan (doubling): lmax=6 -> c=(1,2,2); avail levels after stages: 2,4,6
  int c1 = 0, c2 = 0, c3 = 0;
  {
    int m = 1, cs[3] = {0, 0, 0}, i = 0;
    while (m < lmax && i < 3) { int c = lmax - m; if (c > m) c = m; cs[i++] = c; m += c; }
    c1 = cs[0]; c2 = cs[1]; c3 = cs[2];
  }
  int av1 = 1 + c1;          // levels available after stage 1
  int av2 = av1 + c2;        // after stage 2

  uint32_t ks0, ks1;
#if JAX_PARTITIONABLE
  tf2x32(0u, 42u, 0u, 1u, ks0, ks1);
#else
  {
    uint32_t a0, b0, a1x, b1x;
    tf2x32(0u, 42u, 0u, 2u, a0, b0);
    tf2x32(0u, 42u, 1u, 3u, a1x, b1x);
    ks0 = b0; ks1 = b1x;
  }
#endif

  // zero header: runCount, maxLdev, hist[64], cursor[64] (130 ints)
  hipMemsetAsync(runCount, 0, 130 * sizeof(int), stream);
  hipLaunchKernelGGL(setup_all, dim3(130), dim3(1024), 0, stream,
                     data, masks, P, initp, POW, PTp, INITROW, POW + 512 * 512,
                     off, lmax, initoff, runs, runCount, maxLdev, hist,
                     KEY0, KEY1, ks0, ks1);

  // Phase 1: GEMM P^2 || sort || need-0 backward + fill_out
  {
    int g = GEMM_TILES * c1;
    int bwdBase = g + SORT_BLOCKS;
    hipLaunchKernelGGL(phase_kernel, dim3(bwdBase + BWD_PHASE_BLOCKS), dim3(256), 0, stream,
                       1, g, 1, bwdBase, 0, 0, 0,
                       data, masks, wsF, off, KEY0, KEY1, runs, runCount,
                       maxLdev, hist, cursor, runsSorted, out, lmax);
  }
  // Phase 2: GEMM P^3,P^4 || need-1 backward
  {
    int g = GEMM_TILES * c2;
    hipLaunchKernelGGL(phase_kernel, dim3(g + BWD_PHASE_BLOCKS), dim3(256), 0, stream,
                       2, g, 2, g, 1, av1 - 1, 0,
                       data, masks, wsF, off, KEY0, KEY1, runs, runCount,
                       maxLdev, hist, cursor, runsSorted, out, lmax);
  }
  // Phase 3: GEMM P^5,P^6 || need-[av1, av2-1] backward
  {
    int g = GEMM_TILES * c3;
    hipLaunchKernelGGL(phase_kernel, dim3(g + BWD_PHASE_BLOCKS), dim3(256), 0, stream,
                       3, g, 4, g, av1, av2 - 1, 0,
                       data, masks, wsF, off, KEY0, KEY1, runs, runCount,
                       maxLdev, hist, cursor, runsSorted, out, lmax);
  }
  // Phase 4: need >= av2 backward, LPT over sorted runs (longest first)
  hipLaunchKernelGGL(phase_kernel, dim3(FINAL_BLOCKS), dim3(256), 0, stream,
                     4, 0, 0, 0, av2, lmax - 1, 1,
                     data, masks, wsF, off, KEY0, KEY1, runs, runCount,
                     maxLdev, hist, cursor, runsSorted, out, lmax);
}

// Round 9
// 304.093 us; speedup vs baseline: 1.1516x; 1.1516x over previous
//
#include <hip/hip_runtime.h>
#include <stdint.h>

// MarkovChain FFBS: B=64, T=1024, K=512, I=4
// R20 = R16 (proven 299.7us) + two ISOLATED backward scheduler tweaks.
// (R17 spin-gates: atomic storm, 2.2ms. R18 chain-spreading: FETCH 2.3x,
// reverted. R19 phase pipeline: occupancy poisoned, 350us. All reverted;
// this keeps R16's exact mapping: block = run's 4 chains, LPT sorted.)
//   1. s_setprio(1) on first-pass units of blocks < 1024 (= sorted ranks
//      0..1023, the longest runs; block-uniform, k==0 only). Critical
//      serial chains (~40-60 dependent steps) get SIMD issue preference
//      during the contended phase instead of 1/8 fair-share.
//   2. zigzag pass pairing: pass k odd takes rank NW-1-wid (longest+
//      shortest = true LPT). Algebra keeps a run's 4 chains on ONE block
//      (u>>2 uniform across the block's 4 waves) -> msg-row L2 sharing
//      preserved (FETCH must stay ~20.5MB; R18's 47MB was the spreading).
// Per-k values bit-identical to R11..R19 -> absmax 0.

#define JAX_PARTITIONABLE 1

#define B_ 64
#define T_ 1024
#define K_ 512
#define I_ 4
#define NCHAIN (B_ * I_)
#define POWSLOT (513 * 512)   // rows 0..511 = P^L, row 512 = init_p @ P^L
#define LMAX_WANT 6
#define MAXRUNS 32769
#define BWD_BLOCKS 8192
#define GEMM_BLOCKS (17 * 16)
#define SORT_BLOCKS 129       // ceil(MAXRUNS / 256)

typedef double f64x4 __attribute__((ext_vector_type(4)));

// ---------------- Threefry-2x32-20 (exact jax semantics) ----------------
__host__ __device__ inline void tf2x32(uint32_t k0, uint32_t k1, uint32_t c0, uint32_t c1,
                                       uint32_t& o0, uint32_t& o1) {
  uint32_t ks2 = k0 ^ k1 ^ 0x1BD11BDAu;
  uint32_t x0 = c0 + k0;
  uint32_t x1 = c1 + k1;
#define TFR(r) { x0 += x1; x1 = (x1 << (r)) | (x1 >> (32 - (r))); x1 ^= x0; }
  TFR(13) TFR(15) TFR(26) TFR(6)
  x0 += k1; x1 += ks2 + 1u;
  TFR(17) TFR(29) TFR(16) TFR(24)
  x0 += ks2; x1 += k0 + 2u;
  TFR(13) TFR(15) TFR(26) TFR(6)
  x0 += k0; x1 += k1 + 3u;
  TFR(17) TFR(29) TFR(16) TFR(24)
  x0 += k1; x1 += ks2 + 4u;
  TFR(13) TFR(15) TFR(26) TFR(6)
  x0 += ks2; x1 += k0 + 5u;
#undef TFR
  o0 = x0; o1 = x1;
}

__device__ inline uint32_t rng_bits(uint32_t kj0, uint32_t kj1, uint32_t e) {
#if JAX_PARTITIONABLE
  uint32_t a, b;
  tf2x32(kj0, kj1, 0u, e, a, b);
  return a ^ b;
#else
  const uint32_t HALF = (uint32_t)(NCHAIN * K_ / 2);
  uint32_t a, b;
  if (e < HALF) { tf2x32(kj0, kj1, e, e + HALF, a, b); return a; }
  else          { tf2x32(kj0, kj1, e - HALF, e, a, b); return b; }
#endif
}

// gumbel scale factor: G = -1/log(u) > 0, so that w*G is a monotone image of
// log(w) + (-log(-log u)). Branch-free log, <=2ulp RELATIVE everywhere
// (incl. u->1: e=0 path computes log(m) via exact m-1 and atanh series).
__device__ inline float gumbel_scale(uint32_t bits) {
  float f = __uint_as_float((bits >> 9) | 0x3F800000u) - 1.0f;
  float u = f + 1.17549435e-38f;            // u in [2^-126, 1)
  int iu = __float_as_int(u);
  float ef = (float)((iu >> 23) - 127);
  float m = __int_as_float((iu & 0x007fffff) | 0x3f800000);   // [1,2)
  int big = m > 1.41421356f;                // reduce to [~0.707, ~1.414)
  m = big ? m * 0.5f : m;
  ef = big ? ef + 1.0f : ef;
  float fm = m - 1.0f;                      // exact (Sterbenz)
  float r = fm * __builtin_amdgcn_rcpf(m + 1.0f);   // atanh arg, |r|<=0.172
  float r2 = r * r;
  float p = fmaf(r2, fmaf(r2, fmaf(r2, fmaf(r2, 0.11111111f, 0.14285715f),
                                   0.2f), 0.33333334f), 1.0f);
  float logu = fmaf(ef, 0.69314718f, (r + r) * p);  // < 0 strictly
  return -__builtin_amdgcn_rcpf(logu);
}

__device__ inline void step_key(uint32_t ks0, uint32_t ks1, int j, uint32_t& kj0, uint32_t& kj1) {
#if JAX_PARTITIONABLE
  tf2x32(ks0, ks1, 0u, (uint32_t)j, kj0, kj1);
#else
  const int N = T_ - 1;
  uint32_t o0, o1;
  int v = 2 * j;
  if (v < N) { tf2x32(ks0, ks1, (uint32_t)v, (uint32_t)(v + N), o0, o1); kj0 = o0; }
  else       { tf2x32(ks0, ks1, (uint32_t)(v - N), (uint32_t)v, o0, o1); kj0 = o1; }
  v = 2 * j + 1;
  if (v < N) { tf2x32(ks0, ks1, (uint32_t)v, (uint32_t)(v + N), o0, o1); kj1 = o0; }
  else       { tf2x32(ks0, ks1, (uint32_t)(v - N), (uint32_t)v, o0, o1); kj1 = o1; }
#endif
}

// ---------------- Merged setup: offsets scan + transpose + V1 + keys ----------------
// Header pre-zeroed via hipMemsetAsync.
// blocks 0..63   : per-b offsets scan, run extraction (LDS-aggregated hist/maxL)
// blocks 64..127 : 64x64 LDS-tiled transpose P -> PTp(+1/K), POW0 copy (same load)
// block 128      : V1 = initp @ P (f64, split-K over 2 halves) + INITROW copy
// block 129      : step keys
__global__ __launch_bounds__(1024) void setup_all(
    const int* __restrict__ data, const float* __restrict__ masks,
    const float* __restrict__ P, const float* __restrict__ initp,
    float* __restrict__ POW0, float* __restrict__ PTp,
    float* __restrict__ INITROW, float* __restrict__ V1,
    int* __restrict__ off, int lmax, int initoff,
    int* __restrict__ runs, int* __restrict__ runCount, int* __restrict__ maxLdev,
    int* __restrict__ hist,
    uint32_t* __restrict__ KEY0, uint32_t* __restrict__ KEY1,
    uint32_t ks0, uint32_t ks1) {
  int blk = blockIdx.x;
  int tid = threadIdx.x;
  if (blk < 64) {
    __shared__ int prevObs[1024];
    __shared__ int nextObs[1024];
    __shared__ int lhist[64];
    __shared__ int lmaxL;
    int b = blk;
    int t = tid;
    bool obs = masks[b * T_ + t] > 0.0f;
    prevObs[t] = obs ? t : -1;
    nextObs[t] = obs ? t : T_;
    if (t < 64) lhist[t] = 0;
    if (t == 0) lmaxL = 1;
    __syncthreads();
    for (int o = 1; o < 1024; o <<= 1) {
      int pv = (t >= o) ? prevObs[t - o] : -1;
      int nv = (t + o < 1024) ? nextObs[t + o] : T_;
      __syncthreads();
      if (pv > prevObs[t]) prevObs[t] = pv;
      if (nv < nextObs[t]) nextObs[t] = nv;
      __syncthreads();
    }
    int t0 = (t > 0) ? prevObs[t - 1] : -1;
    int idx = b * T_ + t;
    if (obs) off[idx] = -1;
    else if (t0 >= 0) {
      int L = t - t0; if (L > lmax) L = lmax;
      off[idx] = (L - 1) * POWSLOT + data[b * T_ + t0] * 512;
    } else if (t == 0) off[idx] = initoff;
    else {
      int L = t; if (L > lmax) L = lmax;
      off[idx] = (L - 1) * POWSLOT + 512 * 512;   // init-chain V row
    }
    if (!obs && t <= T_ - 2 && (t == 0 || masks[b * T_ + t - 1] > 0.0f)) {
      int te = nextObs[t] - 1; if (te > T_ - 2) te = T_ - 2;
      int r = atomicAdd(runCount, 1);   // uniform addr, +1 -> wave-coalesced
      if (r < MAXRUNS) {
        runs[r] = (b << 20) | (t << 10) | te;
        int steps = te - t + 1;
        int bkt = steps < 63 ? steps : 63;
        atomicAdd(&lhist[bkt], 1);                 // LDS atomic
        int maxL = (t == 0) ? te : (te - t + 1);
        if (maxL > 1) atomicMax(&lmaxL, maxL);     // LDS atomic
      }
    }
    __syncthreads();
    if (t < 64) {
      int c = lhist[t];
      if (c) atomicAdd(&hist[t], c);               // 64 distinct addresses
    }
    if (t == 0) {
      int v = lmaxL;
      if (v > 1) atomicMax(maxLdev, v);            // one per block
    }
  } else if (blk < 128) {
    // 64x64 tile transpose, both sides coalesced; POW0 copy reuses the load.
    __shared__ float Tls[64][65];
    int tt = blk - 64, tr = tt >> 3, tc = tt & 7;
    int r = tid >> 4, c4 = (tid & 15) << 2;
    int src = ((tr << 6) + r) * 512 + (tc << 6) + c4;
    float4 v = *(const float4*)(P + src);
    *(float4*)(POW0 + src) = v;
    Tls[c4 + 0][r] = v.x;
    Tls[c4 + 1][r] = v.y;
    Tls[c4 + 2][r] = v.z;
    Tls[c4 + 3][r] = v.w;
    __syncthreads();
    const float q = 0.001953125f;   // + 1/K, bit-identical to inline add
    float4 w;
    w.x = Tls[r][c4 + 0] + q;
    w.y = Tls[r][c4 + 1] + q;
    w.z = Tls[r][c4 + 2] + q;
    w.w = Tls[r][c4 + 3] + q;
    *(float4*)(PTp + ((tc << 6) + r) * 512 + (tr << 6) + c4) = w;
  } else if (blk == 128) {
    // V1[c] = sum_j initp[j] * P[j][c], f64, split across 2 thread halves
    __shared__ double vred[512];
    int c = tid & 511, h = tid >> 9;
    const float* Ph = P + h * 256 * 512;
    const float* ih = initp + h * 256;
    double acc = 0.0;
    for (int j = 0; j < 256; ++j) acc += (double)ih[j] * (double)Ph[j * 512 + c];
    if (h == 0) vred[c] = acc;
    __syncthreads();
    if (h == 1) V1[c] = (float)(vred[c] + acc);
    if (tid < 512) INITROW[tid] = initp[tid];
  } else {
    if (tid < T_ - 1) {
      uint32_t a, b;
      step_key(ks0, ks1, tid, a, b);
      KEY0[tid] = a; KEY1[tid] = b;
    }
  }
}

// ---------------- Power GEMM via f64 MFMA (self-calibrating D layout) ----------------
// 32x32 block tile, 4 waves (2x2 of 16x16), Kc=32 chunks, reg-prefetch.
// First launch carries SORT_BLOCKS extra blocks (x >= GEMM_BLOCKS, y == 0)
// that counting-sort-scatter runs into runsSorted (descending step count).
// Scatter uses LDS-staged ranks: one global atomicAdd per (block,bucket).
__global__ __launch_bounds__(256) void power_gemm_mfma(
    float* __restrict__ POW, int m, int lmax, const int* __restrict__ maxLdev,
    int sortN, const int* __restrict__ runs, const int* __restrict__ runCount,
    const int* __restrict__ hist, int* __restrict__ cursor,
    int* __restrict__ runsSorted) {
  if (blockIdx.x >= GEMM_BLOCKS) {
    if (sortN && blockIdx.y == 0) {
      __shared__ int lhist2[64];
      __shared__ int gbase[64];
      __shared__ int sbase[64];
      int tid = threadIdx.x;
      int i = (blockIdx.x - GEMM_BLOCKS) * 256 + tid;
      int total = *runCount; if (total > MAXRUNS) total = MAXRUNS;
      bool valid = i < total;
      if (tid < 64) lhist2[tid] = 0;
      __syncthreads();
      int r = 0, bkt = 0, lr = 0;
      if (valid) {
        r = runs[i];
        int ta = (r >> 10) & 1023, tb = r & 1023;
        int steps = tb - ta + 1;
        bkt = steps < 63 ? steps : 63;
        lr = atomicAdd(&lhist2[bkt], 1);         // LDS: rank within block
      }
      __syncthreads();
      if (tid < 64) {
        int c = lhist2[tid];
        gbase[tid] = c ? atomicAdd(&cursor[tid], c) : 0;   // 1 per (block,bucket)
        int s = 0;
        for (int l = tid + 1; l < 64; ++l) s += hist[l];   // suffix base (desc order)
        sbase[tid] = s;
      }
      __syncthreads();
      if (valid) runsSorted[sbase[bkt] + gbase[bkt] + lr] = r;
    }
    return;
  }
  int y = blockIdx.y;
  {
    int gate = *maxLdev; if (gate > lmax) gate = lmax;
    if (y + 1 + m > gate) return;
  }
  const float* A  = POW + (size_t)y * POWSLOT;
  const float* Bm = POW + (size_t)(m - 1) * POWSLOT;
  float* C        = POW + (size_t)(y + m) * POWSLOT;
  __shared__ double As[32][33];   // [k][r]
  __shared__ double Bs[32][33];   // [k][c]
  int tid = threadIdx.x;
  int lane = tid & 63;
  int wv = tid >> 6;              // wave 0..3
  int wr = wv >> 1, wc = wv & 1;  // 2x2 wave grid
  int q = lane >> 4, r16 = lane & 15;
  int r0 = (blockIdx.x >> 4) * 32;   // 17 row tiles cover 513 rows
  int c0 = (blockIdx.x & 15) * 32;   // 16 col tiles

  // --- calibrate D mapping: (lane,reg) -> (i,j). Exact integer probes. ---
  f64x4 z = {0.0, 0.0, 0.0, 0.0};
  f64x4 d1 = __builtin_amdgcn_mfma_f64_16x16x4f64((double)r16, 1.0, z, 0, 0, 0);   // D=4i
  f64x4 d2 = __builtin_amdgcn_mfma_f64_16x16x4f64(1.0, (double)r16, z, 0, 0, 0);   // D=4j
  int ir[4], ic[4];
#pragma unroll
  for (int v = 0; v < 4; ++v) {
    ir[v] = (((int)d1[v]) >> 2) & 15;
    ic[v] = (((int)d2[v]) >> 2) & 15;
  }

  // staging: thread loads 4 consecutive f32 of an A row and a B row.
  int sr = tid >> 3;                 // 0..31
  int sk4 = (tid & 7) * 4;           // 0,4,..,28
  int ar = r0 + sr; if (ar > 512) ar = 512;   // clamp (stores guarded)

  f64x4 acc = {0.0, 0.0, 0.0, 0.0};
  float4 av = *(const float4*)(A + (size_t)ar * 512 + sk4);
  float4 bv = *(const float4*)(Bm + (size_t)sr * 512 + c0 + sk4);
  for (int kc = 0; kc < 512; kc += 32) {
    __syncthreads();                 // previous chunk's LDS reads done
    As[sk4 + 0][sr] = (double)av.x;
    As[sk4 + 1][sr] = (double)av.y;
    As[sk4 + 2][sr] = (double)av.z;
    As[sk4 + 3][sr] = (double)av.w;
    Bs[sr][sk4 + 0] = (double)bv.x;
    Bs[sr][sk4 + 1] = (double)bv.y;
    Bs[sr][sk4 + 2] = (double)bv.z;
    Bs[sr][sk4 + 3] = (double)bv.w;
    int kn = (kc + 32 < 512) ? kc + 32 : 480;  // clamped (last prefetch unused)
    av = *(const float4*)(A + (size_t)ar * 512 + kn + sk4);
    bv = *(const float4*)(Bm + (size_t)(kn + sr) * 512 + c0 + sk4);
    __syncthreads();
#pragma unroll
    for (int ks = 0; ks < 8; ++ks) {
      double a = As[ks * 4 + q][wr * 16 + r16];
      double b = Bs[ks * 4 + q][wc * 16 + r16];
      acc = __builtin_amdgcn_mfma_f64_16x16x4f64(a, b, acc, 0, 0, 0);
    }
  }
#pragma unroll
  for (int v = 0; v < 4; ++v) {
    int gr = r0 + wr * 16 + ir[v];
    int gc = c0 + wc * 16 + ic[v];
    if (gr < 513) C[(size_t)gr * 512 + gc] = (float)acc[v];
  }
}

// ---------------- Backward sampling: wave-per-(run,chain), LPT + zigzag + prio ----------------
// Lane l owns k = 8l..8l+7 (float4x2 msg/ptp loads). Argmax via fmaxf
// butterfly + ballot (lowest lane with max = smallest k). Per-k values
// bit-identical to R11..R19.
// Pass k even: u = k*NW + wid; pass k odd: u = k*NW + (NW-1-wid)
//   -> zigzag pairs longest with shortest (true LPT), AND keeps a run's
//      4 chains on one block in both parities (u>>2 uniform over wv).
// First-pass units of blocks < 1024 (sorted ranks 0..1023 = longest runs)
// run at s_setprio(1): critical chains get issue preference while full.
__global__ __launch_bounds__(256) void backward_run(
    const int* __restrict__ data, const float* __restrict__ masks,
    const float* __restrict__ wsF, const int* __restrict__ off,
    const float* __restrict__ PTp,
    const uint32_t* __restrict__ KEY0, const uint32_t* __restrict__ KEY1,
    const int* __restrict__ runs, const int* __restrict__ runCount,
    int* __restrict__ out) {
  // folded fill_out: deterministic outputs (observed t, and t = T-1)
  {
    int id = blockIdx.x * 256 + threadIdx.x;
    if (id < NCHAIN * T_) {
      int t = id & (T_ - 1);
      int b = id >> 12;               // id>>10 = chain, chain>>2 = b
      if (t == T_ - 1 || masks[b * T_ + t] > 0.0f) out[id] = data[b * T_ + t];
    }
  }
  int lane = threadIdx.x & 63;
  int wv = threadIdx.x >> 6;
  int wid = blockIdx.x * 4 + wv;
  const int NW = BWD_BLOCKS * 4;
  int total = *runCount;
  if (total > MAXRUNS) total = MAXRUNS;
  total <<= 2;                        // units = runs x 4 chains
  const float* wsL = wsF + (lane << 3);
  const float* ptL = PTp + (lane << 3);
  bool priBlk = (blockIdx.x < 1024);  // sorted ranks 0..1023 on pass 0
  for (int k = 0; k * NW < total; ++k) {
    int u = k * NW + ((k & 1) ? (NW - 1 - wid) : wid);
    if (u >= total) continue;
    bool pri = priBlk && (k == 0);
    if (pri) __builtin_amdgcn_s_setprio(1);
    int run = runs[u >> 2];
    int ci = u & 3;
    int b = run >> 20, ta = (run >> 10) & 1023, tb = run & 1023;
    int s = data[b * T_ + tb + 1];    // mask=1 or t=T-1: deterministic anchor
    uint32_t ebase = ((uint32_t)b << 11) | ((uint32_t)ci << 9) | ((uint32_t)(lane << 3));
    const int* offb = off + b * T_;
    int* outp = out + (((b << 2) | ci) * T_);
    for (int t = tb; t >= ta; --t) {
      int j = (T_ - 2) - t;
      uint32_t kj0 = KEY0[j], kj1 = KEY1[j];
      int o = offb[t];
      float4 m0 = *(const float4*)(wsL + o);
      float4 m1 = *(const float4*)(wsL + o + 4);
      const float* prow = ptL + ((size_t)s << 9);
      float4 p0 = *(const float4*)(prow);
      float4 p1 = *(const float4*)(prow + 4);
      float x0 = fmaf(m0.x, p0.x, 1e-20f) * gumbel_scale(rng_bits(kj0, kj1, ebase + 0u));
      float x1 = fmaf(m0.y, p0.y, 1e-20f) * gumbel_scale(rng_bits(kj0, kj1, ebase + 1u));
      float x2 = fmaf(m0.z, p0.z, 1e-20f) * gumbel_scale(rng_bits(kj0, kj1, ebase + 2u));
      float x3 = fmaf(m0.w, p0.w, 1e-20f) * gumbel_scale(rng_bits(kj0, kj1, ebase + 3u));
      float x4 = fmaf(m1.x, p1.x, 1e-20f) * gumbel_scale(rng_bits(kj0, kj1, ebase + 4u));
      float x5 = fmaf(m1.y, p1.y, 1e-20f) * gumbel_scale(rng_bits(kj0, kj1, ebase + 5u));
      float x6 = fmaf(m1.z, p1.z, 1e-20f) * gumbel_scale(rng_bits(kj0, kj1, ebase + 6u));
      float x7 = fmaf(m1.w, p1.w, 1e-20f) * gumbel_scale(rng_bits(kj0, kj1, ebase + 7u));
      // local argmax, strict > keeps smallest j on ties
      float bv = x0; int bj = 0;
      if (x1 > bv) { bv = x1; bj = 1; }
      if (x2 > bv) { bv = x2; bj = 2; }
      if (x3 > bv) { bv = x3; bj = 3; }
      if (x4 > bv) { bv = x4; bj = 4; }
      if (x5 > bv) { bv = x5; bj = 5; }
      if (x6 > bv) { bv = x6; bj = 6; }
      if (x7 > bv) { bv = x7; bj = 7; }
      // wave max (butterfly -> all lanes hold identical max)
      float wm = bv;
#pragma unroll
      for (int d = 1; d < 64; d <<= 1) wm = fmaxf(wm, __shfl_xor(wm, d));
      unsigned long long bal = __ballot(bv == wm);
      int wl = __ffsll(bal) - 1;       // lowest lane with the max = smallest k
      int jw = __shfl(bj, wl);
      s = (wl << 3) + jw;              // uniform across wave
      if (lane == 0) outp[t] = s;
    }
    if (pri) __builtin_amdgcn_s_setprio(0);
  }
}

// ---------------- Launcher ----------------
extern "C" void kernel_launch(void* const* d_in, const int* in_sizes, int n_in,
                              void* d_out, int out_size, void* d_ws, size_t ws_size,
                              hipStream_t stream) {
  const int* data = (const int*)d_in[0];
  const float* masks = (const float*)d_in[1];
  const float* initp = (const float*)d_in[2];
  const float* P = (const float*)d_in[3];
  int* out = (int*)d_out;

  int lmax = LMAX_WANT;
  {
    long long fixed = 512LL * 512 + 512 + (long long)B_ * T_ + 2 * (T_ - 1)
                      + 2LL * MAXRUNS + 256;
    long long avail = (long long)(ws_size / 4) - fixed;
    long long fit = avail / POWSLOT;
    if (fit < lmax) lmax = (fit < 1) ? 1 : (int)fit;
  }
  float* wsF = (float*)d_ws;
  float* POW = wsF;
  float* PTp = wsF + (size_t)lmax * POWSLOT;
  float* INITROW = PTp + 512 * 512;
  int* off = (int*)(INITROW + 512);
  uint32_t* KEY0 = (uint32_t*)(off + B_ * T_);
  uint32_t* KEY1 = KEY0 + (T_ - 1);
  int* runs = (int*)(KEY1 + (T_ - 1));
  int* runCount = runs + MAXRUNS;
  int* maxLdev = runCount + 1;
  int* histcur = runCount + 2;        // hist[64] then cursor[64]
  int* hist = histcur;
  int* cursor = histcur + 64;
  int* runsSorted = histcur + 128;
  int initoff = lmax * POWSLOT + 512 * 512;   // INITROW position in floats

  uint32_t ks0, ks1;
#if JAX_PARTITIONABLE
  tf2x32(0u, 42u, 0u, 1u, ks0, ks1);
#else
  {
    uint32_t a0, b0, a1, b1;
    tf2x32(0u, 42u, 0u, 2u, a0, b0);
    tf2x32(0u, 42u, 1u, 3u, a1, b1);
    ks0 = b0; ks1 = b1;
  }
#endif

  // zero header: runCount, maxLdev, hist[64], cursor[64] (130 ints).
  hipMemsetAsync(runCount, 0, 130 * sizeof(int), stream);
  hipLaunchKernelGGL(setup_all, dim3(130), dim3(1024), 0, stream,
                     data, masks, P, initp, POW, PTp, INITROW, POW + 512 * 512,
                     off, lmax, initoff, runs, runCount, maxLdev, hist,
                     KEY0, KEY1, ks0, ks1);
  int m = 1, first = 1;
  while (m < lmax) {
    int count = lmax - m; if (count > m) count = m;
    hipLaunchKernelGGL(power_gemm_mfma,
                       dim3(GEMM_BLOCKS + (first ? SORT_BLOCKS : 0), count), dim3(256), 0, stream,
                       POW, m, lmax, maxLdev,
                       first, runs, runCount, hist, cursor, runsSorted);
    first = 0;
    m += count;
  }
  if (first) {
    // lmax == 1: GEMM blocks gate off in-kernel; sort blocks still run.
    hipLaunchKernelGGL(power_gemm_mfma,
                       dim3(GEMM_BLOCKS + SORT_BLOCKS, 1), dim3(256), 0, stream,
                       POW, 1, lmax, maxLdev,
                       1, runs, runCount, hist, cursor, runsSorted);
  }
  hipLaunchKernelGGL(backward_run, dim3(BWD_BLOCKS), dim3(256), 0, stream,
                     data, masks, wsF, off, PTp, KEY0, KEY1, runsSorted, runCount, out);
}

// Round 10
// 294.862 us; speedup vs baseline: 1.1876x; 1.0313x over previous
//
#include <hip/hip_runtime.h>
#include <stdint.h>

// MarkovChain FFBS: B=64, T=1024, K=512, I=4
// R21 = R16 backward (verbatim; fastest measured, 176us / FETCH 20.5MB)
// + non-backward restructure (launch count 6 -> 5):
//   - GEMM stage 1 (P^2) folded INTO setup_all: P^2 = P*P needs only the
//     input P (ready at launch). 256 tile-blocks compute rows 0..511
//     reading P directly; block 128 computes row 512 (V2 = f32(V1)*P,
//     f64 serial -- summation-order delta ~1e-16, far below the
//     f32-forward vs f64-powers delta already tolerated at absmax 0).
//   - offsets scan via __ballot bit-masks (2 barriers, was 20).
//   - sort rides the m=2 GEMM launch (free blocks, LDS-staged as R15).
// Scheduler experiments closed: R17 spin-gates (atomic storm), R18
// spreading (FETCH 2.3x), R19 phases (occupancy poison), R20 setprio/
// zigzag (neutral) -- all reverted. Per-k values bit-identical -> absmax 0.

#define JAX_PARTITIONABLE 1

#define B_ 64
#define T_ 1024
#define K_ 512
#define I_ 4
#define NCHAIN (B_ * I_)
#define POWSLOT (513 * 512)   // rows 0..511 = P^L, row 512 = init_p @ P^L
#define LMAX_WANT 6
#define MAXRUNS 32769
#define BWD_BLOCKS 8192
#define GEMM_BLOCKS (17 * 16)
#define SORT_BLOCKS 129       // ceil(MAXRUNS / 256)
#define SETUP_GEMM_TILES 256  // 16x16 tiles of 32x32 covering 512x512

typedef double f64x4 __attribute__((ext_vector_type(4)));

// ---------------- Threefry-2x32-20 (exact jax semantics) ----------------
__host__ __device__ inline void tf2x32(uint32_t k0, uint32_t k1, uint32_t c0, uint32_t c1,
                                       uint32_t& o0, uint32_t& o1) {
  uint32_t ks2 = k0 ^ k1 ^ 0x1BD11BDAu;
  uint32_t x0 = c0 + k0;
  uint32_t x1 = c1 + k1;
#define TFR(r) { x0 += x1; x1 = (x1 << (r)) | (x1 >> (32 - (r))); x1 ^= x0; }
  TFR(13) TFR(15) TFR(26) TFR(6)
  x0 += k1; x1 += ks2 + 1u;
  TFR(17) TFR(29) TFR(16) TFR(24)
  x0 += ks2; x1 += k0 + 2u;
  TFR(13) TFR(15) TFR(26) TFR(6)
  x0 += k0; x1 += k1 + 3u;
  TFR(17) TFR(29) TFR(16) TFR(24)
  x0 += k1; x1 += ks2 + 4u;
  TFR(13) TFR(15) TFR(26) TFR(6)
  x0 += ks2; x1 += k0 + 5u;
#undef TFR
  o0 = x0; o1 = x1;
}

__device__ inline uint32_t rng_bits(uint32_t kj0, uint32_t kj1, uint32_t e) {
#if JAX_PARTITIONABLE
  uint32_t a, b;
  tf2x32(kj0, kj1, 0u, e, a, b);
  return a ^ b;
#else
  const uint32_t HALF = (uint32_t)(NCHAIN * K_ / 2);
  uint32_t a, b;
  if (e < HALF) { tf2x32(kj0, kj1, e, e + HALF, a, b); return a; }
  else          { tf2x32(kj0, kj1, e - HALF, e, a, b); return b; }
#endif
}

// gumbel scale factor: G = -1/log(u) > 0, monotone image of log(w)+gumbel.
// Branch-free log, <=2ulp RELATIVE everywhere (incl. u->1).
__device__ inline float gumbel_scale(uint32_t bits) {
  float f = __uint_as_float((bits >> 9) | 0x3F800000u) - 1.0f;
  float u = f + 1.17549435e-38f;            // u in [2^-126, 1)
  int iu = __float_as_int(u);
  float ef = (float)((iu >> 23) - 127);
  float m = __int_as_float((iu & 0x007fffff) | 0x3f800000);   // [1,2)
  int big = m > 1.41421356f;                // reduce to [~0.707, ~1.414)
  m = big ? m * 0.5f : m;
  ef = big ? ef + 1.0f : ef;
  float fm = m - 1.0f;                      // exact (Sterbenz)
  float r = fm * __builtin_amdgcn_rcpf(m + 1.0f);   // atanh arg, |r|<=0.172
  float r2 = r * r;
  float p = fmaf(r2, fmaf(r2, fmaf(r2, fmaf(r2, 0.11111111f, 0.14285715f),
                                   0.2f), 0.33333334f), 1.0f);
  float logu = fmaf(ef, 0.69314718f, (r + r) * p);  // < 0 strictly
  return -__builtin_amdgcn_rcpf(logu);
}

__device__ inline void step_key(uint32_t ks0, uint32_t ks1, int j, uint32_t& kj0, uint32_t& kj1) {
#if JAX_PARTITIONABLE
  tf2x32(ks0, ks1, 0u, (uint32_t)j, kj0, kj1);
#else
  const int N = T_ - 1;
  uint32_t o0, o1;
  int v = 2 * j;
  if (v < N) { tf2x32(ks0, ks1, (uint32_t)v, (uint32_t)(v + N), o0, o1); kj0 = o0; }
  else       { tf2x32(ks0, ks1, (uint32_t)(v - N), (uint32_t)v, o0, o1); kj0 = o1; }
  v = 2 * j + 1;
  if (v < N) { tf2x32(ks0, ks1, (uint32_t)v, (uint32_t)(v + N), o0, o1); kj1 = o0; }
  else       { tf2x32(ks0, ks1, (uint32_t)(v - N), (uint32_t)v, o0, o1); kj1 = o1; }
#endif
}

// ---------------- GEMM tile core (f64 MFMA, self-calibrating D layout) ----------------
__device__ __forceinline__ void gemm_tile_core(
    const float* __restrict__ A, const float* __restrict__ Bm, float* __restrict__ C,
    int r0, int c0, int maxRowA, int writeRows,
    double (*As)[33], double (*Bs)[33], int tid) {
  int lane = tid & 63;
  int wv = tid >> 6;
  int wr = wv >> 1, wc = wv & 1;
  int q = lane >> 4, r16 = lane & 15;
  f64x4 z = {0.0, 0.0, 0.0, 0.0};
  f64x4 d1 = __builtin_amdgcn_mfma_f64_16x16x4f64((double)r16, 1.0, z, 0, 0, 0);   // D=4i
  f64x4 d2 = __builtin_amdgcn_mfma_f64_16x16x4f64(1.0, (double)r16, z, 0, 0, 0);   // D=4j
  int ir[4], ic[4];
#pragma unroll
  for (int v = 0; v < 4; ++v) {
    ir[v] = (((int)d1[v]) >> 2) & 15;
    ic[v] = (((int)d2[v]) >> 2) & 15;
  }
  int sr = tid >> 3;
  int sk4 = (tid & 7) * 4;
  int ar = r0 + sr; if (ar > maxRowA) ar = maxRowA;   // clamp (stores guarded)
  f64x4 acc = {0.0, 0.0, 0.0, 0.0};
  float4 av = *(const float4*)(A + (size_t)ar * 512 + sk4);
  float4 bv = *(const float4*)(Bm + (size_t)sr * 512 + c0 + sk4);
  for (int kc = 0; kc < 512; kc += 32) {
    __syncthreads();                 // previous chunk's LDS reads done
    As[sk4 + 0][sr] = (double)av.x;
    As[sk4 + 1][sr] = (double)av.y;
    As[sk4 + 2][sr] = (double)av.z;
    As[sk4 + 3][sr] = (double)av.w;
    Bs[sr][sk4 + 0] = (double)bv.x;
    Bs[sr][sk4 + 1] = (double)bv.y;
    Bs[sr][sk4 + 2] = (double)bv.z;
    Bs[sr][sk4 + 3] = (double)bv.w;
    int kn = (kc + 32 < 512) ? kc + 32 : 480;  // clamped (last prefetch unused)
    av = *(const float4*)(A + (size_t)ar * 512 + kn + sk4);
    bv = *(const float4*)(Bm + (size_t)(kn + sr) * 512 + c0 + sk4);
    __syncthreads();
#pragma unroll
    for (int ks = 0; ks < 8; ++ks) {
      double a = As[ks * 4 + q][wr * 16 + r16];
      double b = Bs[ks * 4 + q][wc * 16 + r16];
      acc = __builtin_amdgcn_mfma_f64_16x16x4f64(a, b, acc, 0, 0, 0);
    }
  }
#pragma unroll
  for (int v = 0; v < 4; ++v) {
    int gr = r0 + wr * 16 + ir[v];
    int gc = c0 + wc * 16 + ic[v];
    if (gr < writeRows) C[(size_t)gr * 512 + gc] = (float)acc[v];
  }
}

// ---------------- Merged setup: scan + transpose + V1/V2 + keys + P^2 ----------------
// Header pre-zeroed via hipMemsetAsync. 386 blocks x 1024 threads:
//  0..63   : per-b offsets scan via __ballot masks (2 barriers), run
//            extraction, LDS-aggregated hist/maxL flush (R15 pattern)
//  64..127 : 64x64 LDS-tiled transpose P -> PTp(+1/K), POW0 copy
//  128     : V1 = initp@P (f64), INITROW, then V2 = f32(V1)@P -> slot1 row 512
//  129     : step keys
//  130..385: P^2 rows 0..511 (gemm tiles reading INPUT P; tid<256)
__global__ __launch_bounds__(1024) void setup_all(
    const int* __restrict__ data, const float* __restrict__ masks,
    const float* __restrict__ P, const float* __restrict__ initp,
    float* __restrict__ POW0, float* __restrict__ PTp,
    float* __restrict__ INITROW, float* __restrict__ V1,
    int* __restrict__ off, int lmax, int initoff,
    int* __restrict__ runs, int* __restrict__ runCount, int* __restrict__ maxLdev,
    int* __restrict__ hist,
    uint32_t* __restrict__ KEY0, uint32_t* __restrict__ KEY1,
    uint32_t ks0, uint32_t ks1) {
  __shared__ double smem[2112];   // 16896 B, aliased per role
  int blk = blockIdx.x;
  int tid = threadIdx.x;
  if (blk < 64) {
    unsigned long long* wmask = (unsigned long long*)smem;     // 16
    int* pIncl = (int*)(smem + 16);                            // 1024
    int* lhist = (int*)(smem + 528);                           // 64
    int* lmaxL = (int*)(smem + 560);
    int b = blk, t = tid, l = t & 63, w = t >> 6;
    bool obs = masks[b * T_ + t] > 0.0f;
    unsigned long long mw = __ballot(obs);
    if (l == 0) wmask[w] = mw;
    if (t < 64) lhist[t] = 0;
    if (t == 0) *lmaxL = 1;
    __syncthreads();
    // prev observed index <= t (inclusive), else -1
    unsigned long long below = mw & (~0ull >> (63 - l));
    int pv;
    if (below) pv = (w << 6) + 63 - __builtin_clzll(below);
    else {
      pv = -1;
      for (int w2 = w - 1; w2 >= 0; --w2) {
        unsigned long long m2 = wmask[w2];
        if (m2) { pv = (w2 << 6) + 63 - __builtin_clzll(m2); break; }
      }
    }
    pIncl[t] = pv;
    // next observed index >= t, else T_
    unsigned long long above = mw & (~0ull << l);
    int nv;
    if (above) nv = (w << 6) + __builtin_ctzll(above);
    else {
      nv = T_;
      for (int w2 = w + 1; w2 < 16; ++w2) {
        unsigned long long m2 = wmask[w2];
        if (m2) { nv = (w2 << 6) + __builtin_ctzll(m2); break; }
      }
    }
    __syncthreads();
    int t0 = (t > 0) ? pIncl[t - 1] : -1;
    int idx = b * T_ + t;
    if (obs) off[idx] = -1;
    else if (t0 >= 0) {
      int L = t - t0; if (L > lmax) L = lmax;
      off[idx] = (L - 1) * POWSLOT + data[b * T_ + t0] * 512;
    } else if (t == 0) off[idx] = initoff;
    else {
      int L = t; if (L > lmax) L = lmax;
      off[idx] = (L - 1) * POWSLOT + 512 * 512;   // init-chain V row
    }
    if (!obs && t <= T_ - 2 && (t == 0 || masks[b * T_ + t - 1] > 0.0f)) {
      int te = nv - 1; if (te > T_ - 2) te = T_ - 2;
      int r = atomicAdd(runCount, 1);   // uniform addr, wave-coalesced
      if (r < MAXRUNS) {
        runs[r] = (b << 20) | (t << 10) | te;
        int steps = te - t + 1;
        int bkt = steps < 63 ? steps : 63;
        atomicAdd(&lhist[bkt], 1);                 // LDS atomic
        int maxL = (t == 0) ? te : (te - t + 1);
        if (maxL > 1) atomicMax(lmaxL, maxL);      // LDS atomic
      }
    }
    __syncthreads();
    if (t < 64) {
      int c = lhist[t];
      if (c) atomicAdd(&hist[t], c);               // 64 distinct addresses
    }
    if (t == 0) {
      int v = *lmaxL;
      if (v > 1) atomicMax(maxLdev, v);            // one per block
    }
  } else if (blk < 128) {
    // 64x64 tile transpose, both sides coalesced; POW0 copy reuses the load.
    float (*Tls)[65] = (float(*)[65])smem;
    int tt = blk - 64, tr = tt >> 3, tc = tt & 7;
    int r = tid >> 4, c4 = (tid & 15) << 2;
    int src = ((tr << 6) + r) * 512 + (tc << 6) + c4;
    float4 v = *(const float4*)(P + src);
    *(float4*)(POW0 + src) = v;
    Tls[c4 + 0][r] = v.x;
    Tls[c4 + 1][r] = v.y;
    Tls[c4 + 2][r] = v.z;
    Tls[c4 + 3][r] = v.w;
    __syncthreads();
    const float q = 0.001953125f;   // + 1/K, bit-identical to inline add
    float4 w;
    w.x = Tls[r][c4 + 0] + q;
    w.y = Tls[r][c4 + 1] + q;
    w.z = Tls[r][c4 + 2] + q;
    w.w = Tls[r][c4 + 3] + q;
    *(float4*)(PTp + ((tc << 6) + r) * 512 + (tr << 6) + c4) = w;
  } else if (blk == 128) {
    // V1 = initp @ P (f64, split-K halves); then V2 = f32(V1) @ P.
    double* vred = smem;                  // 512
    float* v1sh = (float*)(smem + 512);   // 512 f32
    int c = tid & 511, h = tid >> 9;
    const float* Ph = P + h * 256 * 512;
    const float* ih = initp + h * 256;
    double acc = 0.0;
    for (int j = 0; j < 256; ++j) acc += (double)ih[j] * (double)Ph[j * 512 + c];
    if (h == 0) vred[c] = acc;
    __syncthreads();
    if (h == 1) {
      float v = (float)(vred[c] + acc);
      V1[c] = v;
      v1sh[c] = v;
    }
    if (tid < 512) INITROW[tid] = initp[tid];
    if (lmax >= 2) {
      __syncthreads();
      double a2 = 0.0;
      const float* vh = v1sh + h * 256;
      for (int j = 0; j < 256; ++j) a2 += (double)vh[j] * (double)Ph[j * 512 + c];
      if (h == 0) vred[c] = a2;
      __syncthreads();
      if (h == 1) POW0[POWSLOT + 512 * 512 + c] = (float)(vred[c] + a2);  // V2
    }
  } else if (blk == 129) {
    if (tid < T_ - 1) {
      uint32_t a, b;
      step_key(ks0, ks1, tid, a, b);
      KEY0[tid] = a; KEY1[tid] = b;
    }
  } else {
    // P^2 rows 0..511: read INPUT P directly (ready at launch).
    if (lmax < 2) return;
    if (tid >= 256) return;   // 12 waves retire; barrier counts remaining 4
    double (*As)[33] = (double(*)[33])smem;
    double (*Bs)[33] = (double(*)[33])(smem + 1056);
    int tx = blk - 130;
    gemm_tile_core(P, P, POW0 + POWSLOT, (tx >> 4) * 32, (tx & 15) * 32,
                   511, 512, As, Bs, tid);
  }
}

// ---------------- Power GEMM stages m>=2 (+ sort on first launch) ----------------
__global__ __launch_bounds__(256) void power_gemm_mfma(
    float* __restrict__ POW, int m, int lmax, const int* __restrict__ maxLdev,
    int sortN, const int* __restrict__ runs, const int* __restrict__ runCount,
    const int* __restrict__ hist, int* __restrict__ cursor,
    int* __restrict__ runsSorted) {
  __shared__ double As[32][33];
  __shared__ double Bs[32][33];
  if (blockIdx.x >= GEMM_BLOCKS) {
    if (sortN && blockIdx.y == 0) {
      // counting-sort scatter, LDS-staged: ONE global atomicAdd per
      // (block,bucket) -- no same-address storms (R14 lesson).
      int* ish = (int*)As;             // lhist2[64], gbase[64], sbase[64]
      int tid = threadIdx.x;
      int i = (blockIdx.x - GEMM_BLOCKS) * 256 + tid;
      int total = *runCount; if (total > MAXRUNS) total = MAXRUNS;
      bool valid = i < total;
      if (tid < 64) ish[tid] = 0;
      __syncthreads();
      int r = 0, bkt = 0, lr = 0;
      if (valid) {
        r = runs[i];
        int ta = (r >> 10) & 1023, tb = r & 1023;
        int steps = tb - ta + 1;
        bkt = steps < 63 ? steps : 63;
        lr = atomicAdd(&ish[bkt], 1);
      }
      __syncthreads();
      if (tid < 64) {
        int c = ish[tid];
        ish[64 + tid] = c ? atomicAdd(&cursor[tid], c) : 0;
        int s = 0;
        for (int l = tid + 1; l < 64; ++l) s += hist[l];
        ish[128 + tid] = s;
      }
      __syncthreads();
      if (valid) runsSorted[ish[128 + bkt] + ish[64 + bkt] + lr] = r;
    }
    return;
  }
  int y = blockIdx.y;
  {
    int gate = *maxLdev; if (gate > lmax) gate = lmax;
    if (y + 1 + m > gate) return;
  }
  gemm_tile_core(POW + (size_t)y * POWSLOT, POW + (size_t)(m - 1) * POWSLOT,
                 POW + (size_t)(y + m) * POWSLOT,
                 (blockIdx.x >> 4) * 32, (blockIdx.x & 15) * 32,
                 512, 513, As, Bs, threadIdx.x);
}

// ---------------- Backward sampling (R16 verbatim): wave-per-(run,chain), LPT ----------------
__global__ __launch_bounds__(256) void backward_run(
    const int* __restrict__ data, const float* __restrict__ masks,
    const float* __restrict__ wsF, const int* __restrict__ off,
    const float* __restrict__ PTp,
    const uint32_t* __restrict__ KEY0, const uint32_t* __restrict__ KEY1,
    const int* __restrict__ runs, const int* __restrict__ runCount,
    int* __restrict__ out) {
  // folded fill_out: deterministic outputs (observed t, and t = T-1)
  {
    int id = blockIdx.x * 256 + threadIdx.x;
    if (id < NCHAIN * T_) {
      int t = id & (T_ - 1);
      int b = id >> 12;               // id>>10 = chain, chain>>2 = b
      if (t == T_ - 1 || masks[b * T_ + t] > 0.0f) out[id] = data[b * T_ + t];
    }
  }
  int lane = threadIdx.x & 63;
  int wv = threadIdx.x >> 6;
  int wid = blockIdx.x * 4 + wv;
  const int NW = BWD_BLOCKS * 4;
  int total = *runCount;
  if (total > MAXRUNS) total = MAXRUNS;
  total <<= 2;                        // units = runs x 4 chains
  const float* wsL = wsF + (lane << 3);
  const float* ptL = PTp + (lane << 3);
  for (int u = wid; u < total; u += NW) {
    int run = runs[u >> 2];
    int ci = u & 3;
    int b = run >> 20, ta = (run >> 10) & 1023, tb = run & 1023;
    int s = data[b * T_ + tb + 1];    // mask=1 or t=T-1: deterministic anchor
    uint32_t ebase = ((uint32_t)b << 11) | ((uint32_t)ci << 9) | ((uint32_t)(lane << 3));
    const int* offb = off + b * T_;
    int* outp = out + (((b << 2) | ci) * T_);
    for (int t = tb; t >= ta; --t) {
      int j = (T_ - 2) - t;
      uint32_t kj0 = KEY0[j], kj1 = KEY1[j];
      int o = offb[t];
      float4 m0 = *(const float4*)(wsL + o);
      float4 m1 = *(const float4*)(wsL + o + 4);
      const float* prow = ptL + ((size_t)s << 9);
      float4 p0 = *(const float4*)(prow);
      float4 p1 = *(const float4*)(prow + 4);
      float x0 = fmaf(m0.x, p0.x, 1e-20f) * gumbel_scale(rng_bits(kj0, kj1, ebase + 0u));
      float x1 = fmaf(m0.y, p0.y, 1e-20f) * gumbel_scale(rng_bits(kj0, kj1, ebase + 1u));
      float x2 = fmaf(m0.z, p0.z, 1e-20f) * gumbel_scale(rng_bits(kj0, kj1, ebase + 2u));
      float x3 = fmaf(m0.w, p0.w, 1e-20f) * gumbel_scale(rng_bits(kj0, kj1, ebase + 3u));
      float x4 = fmaf(m1.x, p1.x, 1e-20f) * gumbel_scale(rng_bits(kj0, kj1, ebase + 4u));
      float x5 = fmaf(m1.y, p1.y, 1e-20f) * gumbel_scale(rng_bits(kj0, kj1, ebase + 5u));
      float x6 = fmaf(m1.z, p1.z, 1e-20f) * gumbel_scale(rng_bits(kj0, kj1, ebase + 6u));
      float x7 = fmaf(m1.w, p1.w, 1e-20f) * gumbel_scale(rng_bits(kj0, kj1, ebase + 7u));
      // local argmax, strict > keeps smallest j on ties
      float bv = x0; int bj = 0;
      if (x1 > bv) { bv = x1; bj = 1; }
      if (x2 > bv) { bv = x2; bj = 2; }
      if (x3 > bv) { bv = x3; bj = 3; }
      if (x4 > bv) { bv = x4; bj = 4; }
      if (x5 > bv) { bv = x5; bj = 5; }
      if (x6 > bv) { bv = x6; bj = 6; }
      if (x7 > bv) { bv = x7; bj = 7; }
      // wave max (butterfly -> all lanes hold identical max)
      float wm = bv;
#pragma unroll
      for (int d = 1; d < 64; d <<= 1) wm = fmaxf(wm, __shfl_xor(wm, d));
      unsigned long long bal = __ballot(bv == wm);
      int wl = __ffsll(bal) - 1;       // lowest lane with the max = smallest k
      int jw = __shfl(bj, wl);
      s = (wl << 3) + jw;              // uniform across wave
      if (lane == 0) outp[t] = s;
    }
  }
}

// ---------------- Launcher ----------------
extern "C" void kernel_launch(void* const* d_in, const int* in_sizes, int n_in,
                              void* d_out, int out_size, void* d_ws, size_t ws_size,
                              hipStream_t stream) {
  const int* data = (const int*)d_in[0];
  const float* masks = (const float*)d_in[1];
  const float* initp = (const float*)d_in[2];
  const float* P = (const float*)d_in[3];
  int* out = (int*)d_out;

  int lmax = LMAX_WANT;
  {
    long long fixed = 512LL * 512 + 512 + (long long)B_ * T_ + 2 * (T_ - 1)
                      + 2LL * MAXRUNS + 256;
    long long avail = (long long)(ws_size / 4) - fixed;
    long long fit = avail / POWSLOT;
    if (fit < lmax) lmax = (fit < 1) ? 1 : (int)fit;
  }
  float* wsF = (float*)d_ws;
  float* POW = wsF;
  float* PTp = wsF + (size_t)lmax * POWSLOT;
  float* INITROW = PTp + 512 * 512;
  int* off = (int*)(INITROW + 512);
  uint32_t* KEY0 = (uint32_t*)(off + B_ * T_);
  uint32_t* KEY1 = KEY0 + (T_ - 1);
  int* runs = (int*)(KEY1 + (T_ - 1));
  int* runCount = runs + MAXRUNS;     // header: [0] runCount, [1] maxLdev,
  int* maxLdev = runCount + 1;        // [2..65] hist, [66..129] cursor
  int* hist = runCount + 2;
  int* cursor = runCount + 66;
  int* runsSorted = runCount + 130;
  int initoff = lmax * POWSLOT + 512 * 512;   // INITROW position in floats

  uint32_t ks0, ks1;
#if JAX_PARTITIONABLE
  tf2x32(0u, 42u, 0u, 1u, ks0, ks1);
#else
  {
    uint32_t a0, b0, a1, b1;
    tf2x32(0u, 42u, 0u, 2u, a0, b0);
    tf2x32(0u, 42u, 1u, 3u, a1, b1);
    ks0 = b0; ks1 = b1;
  }
#endif

  // zero header: runCount, maxLdev, hist[64], cursor[64] (130 ints).
  hipMemsetAsync(runCount, 0, 130 * sizeof(int), stream);
  // setup + P^2 (reads input P only) in one launch
  hipLaunchKernelGGL(setup_all, dim3(130 + SETUP_GEMM_TILES), dim3(1024), 0, stream,
                     data, masks, P, initp, POW, PTp, INITROW, POW + 512 * 512,
                     off, lmax, initoff, runs, runCount, maxLdev, hist,
                     KEY0, KEY1, ks0, ks1);
  // power stages m=2,4 (lmax=6: P3,P4 then P5,P6); sort rides the first
  int m = 2, first = 1;
  while (m < lmax) {
    int count = lmax - m; if (count > m) count = m;
    hipLaunchKernelGGL(power_gemm_mfma,
                       dim3(GEMM_BLOCKS + (first ? SORT_BLOCKS : 0), count), dim3(256), 0, stream,
                       POW, m, lmax, maxLdev,
                       first, runs, runCount, hist, cursor, runsSorted);
    first = 0;
    m += count;
  }
  if (first) {
    // lmax <= 2: GEMM blocks gate off in-kernel; sort blocks still run.
    hipLaunchKernelGGL(power_gemm_mfma,
                       dim3(GEMM_BLOCKS + SORT_BLOCKS, 1), dim3(256), 0, stream,
                       POW, 2, lmax, maxLdev,
                       1, runs, runCount, hist, cursor, runsSorted);
  }
  hipLaunchKernelGGL(backward_run, dim3(BWD_BLOCKS), dim3(256), 0, stream,
                     data, masks, wsF, off, PTp, KEY0, KEY1, runsSorted, runCount, out);
}